// Round 11
// baseline (73.708 us; speedup 1.0000x reference)
//
#include <hip/hip_runtime.h>
#include <hip/hip_bf16.h>

// FeatureEmbedding: out[b, f+1, e] = sum_d relu(x[b,f]*W1[f,d]+b1[f,d]) * W2[f,d,e] + b2[f,e]
//                   out[b, 0,   e] = cls_token[e]
// B=4096, F=64, D=256. Output f32 [4096][65][256].

#define B_  4096
#define F_  64
#define D_  256
#define ORS (65 * 256)   // out row stride (floats)

using f32x4  = __attribute__((ext_vector_type(4))) float;
using s16x8  = __attribute__((ext_vector_type(8))) short;

__device__ __forceinline__ unsigned short to_bf16_bits(float v) {
    __hip_bfloat16 h = __float2bfloat16(v);
    return *reinterpret_cast<unsigned short*>(&h);
}

// ---------------------------------------------------------------------------
// Prep (r10, proven): W2 f32 [f][k][e] -> W2r bf16; unit index
//   (((f*4 + cg)*4 + nt)*8 + ks)*64 + lane   (lane = lhi*16 + llo)
// holds the 8 bf16 of W2[f][k = ks*32+lhi*8 .. +8][n = cg*64+nt*16+llo].
// Wave loads of a (f,cg) stripe are 32 x 1KB contiguous.
// ---------------------------------------------------------------------------
__global__ __launch_bounds__(256) void femb_prep(
    const float* __restrict__ W2, unsigned short* __restrict__ W2r)
{
    const int blk = blockIdx.x;        // f*4 + kq (kq = 64-k quarter)
    const int f   = blk >> 2;
    const int kq  = blk & 3;
    const int t   = threadIdx.x;       // owns output column n = t

    const float* col = W2 + (size_t)f * D_ * D_ + (size_t)(kq * 64) * D_ + t;
    float r[64];
    #pragma unroll
    for (int j = 0; j < 64; ++j) r[j] = col[(size_t)j * D_];

    const int cg  = t >> 6;
    const int nt  = (t >> 4) & 3;
    const int llo = t & 15;

    #pragma unroll
    for (int j8 = 0; j8 < 8; ++j8) {
        union { s16x8 s; unsigned short u[8]; } pk;
        #pragma unroll
        for (int e = 0; e < 8; ++e) pk.u[e] = to_bf16_bits(r[j8 * 8 + e]);
        const int ks   = kq * 2 + (j8 >> 2);
        const int lhi  = j8 & 3;
        const size_t unit = ((size_t)((f * 4 + cg) * 4 + nt) * 8 + ks) * 64 + lhi * 16 + llo;
        *reinterpret_cast<s16x8*>(W2r + unit * 8) = pk.s;
    }
}

// ---------------------------------------------------------------------------
// Main: one block = (feature PAIR 2fp..2fp+1, 256-row group). 512 threads =
// 8 waves; wave w: feature f0 + (w>>2), col-group w&3 (64 cols), B-stripe in
// registers (128 VGPR). M streamed in 8 chunks of 32 rows; register-only
// K-loop (no barriers). Epilogue: per 16-row sub-chunk, all 8 waves deposit
// their 64-col slices (+b2) into one eb buffer -> each output row is a
// 2KB CONTIGUOUS span (features adjacent in e); read back as 128 lanes/row
// f32x4, lgkm-only barriers, stores never vmcnt-drained.
// fp==0 blocks also write the cls row. 1 block/CU (8 waves, ~210 VGPR).
// ---------------------------------------------------------------------------
__global__ __launch_bounds__(512, 2) void femb_main11(
    const float* __restrict__ x,  const float* __restrict__ W1,
    const float* __restrict__ b1, const unsigned short* __restrict__ W2r,
    const float* __restrict__ b2, const float* __restrict__ cls,
    float* __restrict__ out)
{
    __shared__ float w1s[2][D_];
    __shared__ float b1s[2][D_];
    __shared__ float xs[2][256];
    __shared__ __align__(16) float eb[2][16 * 516];  // 16 rows x 512 cols, stride 516

    const int tid  = threadIdx.x;
    const int bid  = blockIdx.x;
    const int fp   = bid & 31;          // feature pair; same-fp blocks -> same XCD
    const int f0   = fp * 2;
    const int row0 = (bid >> 5) << 8;   // 16 row-groups of 256

    {   // stage per-feature vectors + x rows
        const int fl  = tid >> 8;       // 0..1
        const int idx = tid & 255;
        w1s[fl][idx] = W1[(f0 + fl) * D_ + idx];
        b1s[fl][idx] = b1[(f0 + fl) * D_ + idx];
        xs[fl][idx]  = x[(size_t)(row0 + idx) * F_ + f0 + fl];
    }

    const int lane = tid & 63;
    const int w    = tid >> 6;     // wave 0..7
    const int f2   = w >> 2;       // feature within pair
    const int cg   = w & 3;        // 64-col group
    const int llo  = lane & 15;
    const int lhi  = lane >> 4;
    const int f    = f0 + f2;

    // ---- B-stripe -> registers: 32 x 1KB contiguous wave-loads ----
    s16x8 breg[4][8];
    const unsigned short* gb = W2r + (size_t)(f * 4 + cg) * 16384;
    #pragma unroll
    for (int nt = 0; nt < 4; ++nt)
        #pragma unroll
        for (int ks = 0; ks < 8; ++ks)
            breg[nt][ks] = *reinterpret_cast<const s16x8*>(
                gb + ((nt * 8 + ks) * 64 + lane) * 8);

    // b2 folded on the eb-write side (feature-aligned per wave)
    f32x4 b2w[4];
    #pragma unroll
    for (int nt = 0; nt < 4; ++nt)
        b2w[nt] = *reinterpret_cast<const f32x4*>(
            &b2[f * D_ + cg * 64 + nt * 16 + lhi * 4]);
    // cls value for the read phase (lanepos<64 threads only)
    f32x4 clsv = *reinterpret_cast<const f32x4*>(cls + (tid & 63) * 4);

    __syncthreads();   // staging ready

#define EPI_BAR()                                                              \
    do {                                                                       \
        asm volatile("s_waitcnt lgkmcnt(0)" ::: "memory");                     \
        __builtin_amdgcn_s_barrier();                                          \
        asm volatile("" ::: "memory");                                         \
    } while (0)

    for (int ch = 0; ch < 8; ++ch) {
        // ---- K-loop rows [ch*32, ch*32+32): register-only, no barriers ----
        const float xv0 = xs[f2][ch * 32 + llo];
        const float xv1 = xs[f2][ch * 32 + 16 + llo];

        f32x4 acc[2][4];
        #pragma unroll
        for (int mt = 0; mt < 2; ++mt)
            #pragma unroll
            for (int nt = 0; nt < 4; ++nt)
                acc[mt][nt] = (f32x4){0.f, 0.f, 0.f, 0.f};

        #pragma unroll
        for (int ks = 0; ks < 8; ++ks) {
            const int kg = ks * 32 + lhi * 8;
            f32x4 w1a = *reinterpret_cast<const f32x4*>(&w1s[f2][kg]);
            f32x4 w1b = *reinterpret_cast<const f32x4*>(&w1s[f2][kg + 4]);
            f32x4 b1a = *reinterpret_cast<const f32x4*>(&b1s[f2][kg]);
            f32x4 b1b = *reinterpret_cast<const f32x4*>(&b1s[f2][kg + 4]);

            s16x8 afrag[2];
            #pragma unroll
            for (int mt = 0; mt < 2; ++mt) {
                const float xv = mt ? xv1 : xv0;
                union { s16x8 sv; unsigned short u[8]; } pk;
                #pragma unroll
                for (int e = 0; e < 4; ++e) {
                    pk.u[e]     = to_bf16_bits(fmaxf(fmaf(xv, w1a[e], b1a[e]), 0.f));
                    pk.u[e + 4] = to_bf16_bits(fmaxf(fmaf(xv, w1b[e], b1b[e]), 0.f));
                }
                afrag[mt] = pk.sv;
            }

            #pragma unroll
            for (int nt = 0; nt < 4; ++nt)
                #pragma unroll
                for (int mt = 0; mt < 2; ++mt)
                    acc[mt][nt] = __builtin_amdgcn_mfma_f32_16x16x32_bf16(
                        breg[nt][ks], afrag[mt], acc[mt][nt], 0, 0, 0);
        }

        // ---- Epilogue: 2 sub-chunks of 16 rows; 2KB-contiguous row spans ----
        // acc layout (verified): row = ch*32 + mt*16 + llo ;
        //                        col(within feature) = cg*64 + nt*16 + lhi*4 + r
        #pragma unroll
        for (int sc = 0; sc < 2; ++sc) {
            float* ebuf = eb[sc];
            #pragma unroll
            for (int nt = 0; nt < 4; ++nt)
                *reinterpret_cast<f32x4*>(
                    &ebuf[llo * 516 + f2 * 256 + cg * 64 + nt * 16 + lhi * 4])
                    = acc[sc][nt] + b2w[nt];
            EPI_BAR();
            // read: 4 passes x 4 rows; 128 lanes/row -> per-row 2KB contiguous
            const int lanepos = tid & 127;
            #pragma unroll
            for (int i = 0; i < 4; ++i) {
                const int lr = (tid >> 7) + i * 4;       // 0..15
                const size_t grow = (size_t)(row0 + ch * 32 + sc * 16 + lr);
                f32x4 v = *reinterpret_cast<const f32x4*>(&ebuf[lr * 516 + lanepos * 4]);
                *reinterpret_cast<f32x4*>(
                    out + grow * ORS + (size_t)(f0 + 1) * D_ + lanepos * 4) = v;
                if (fp == 0 && lanepos < 64)
                    *reinterpret_cast<f32x4*>(out + grow * ORS + lanepos * 4) = clsv;
            }
            EPI_BAR();  // all reads of ebuf done (store data waited lgkm) -> reusable
        }
    }
#undef EPI_BAR
}

// ---------------------------------------------------------------------------
// Fallback path (round-1, proven) if ws too small: cls kernel + direct main.
// ---------------------------------------------------------------------------
__global__ void femb_cls(const float* __restrict__ cls, float* __restrict__ out)
{
    int i = blockIdx.x * 256 + threadIdx.x;
    int b = i >> 6;
    int q = i & 63;
    f32x4 v = *reinterpret_cast<const f32x4*>(cls + q * 4);
    *reinterpret_cast<f32x4*>(out + (size_t)b * ORS + q * 4) = v;
}

__global__ __launch_bounds__(256, 2) void femb_main_fb(
    const float* __restrict__ x,  const float* __restrict__ W1,
    const float* __restrict__ b1, const float* __restrict__ W2,
    const float* __restrict__ b2, float* __restrict__ out)
{
    __shared__ float w1s[D_];
    __shared__ float b1s[D_];
    __shared__ float xs[128];
    __shared__ __align__(16) unsigned short bW[256][72];

    const int tid  = threadIdx.x;
    const int bid  = blockIdx.x;
    const int f    = bid & 63;
    const int row0 = (bid >> 6) << 7;

    w1s[tid] = W1[f * D_ + tid];
    b1s[tid] = b1[f * D_ + tid];
    if (tid < 128) xs[tid] = x[(size_t)(row0 + tid) * F_ + f];

    const int lane = tid & 63;
    const int wid  = tid >> 6;
    const int wm   = wid >> 1;
    const int wn   = wid & 1;
    const int llo  = lane & 15;
    const int lhi  = lane >> 4;

    __syncthreads();

    float xv[4];
    #pragma unroll
    for (int mt = 0; mt < 4; ++mt) xv[mt] = xs[wm * 64 + mt * 16 + llo];

    f32x4 acc[4][8];
    #pragma unroll
    for (int mt = 0; mt < 4; ++mt)
        #pragma unroll
        for (int nt = 0; nt < 8; ++nt)
            acc[mt][nt] = (f32x4){0.f, 0.f, 0.f, 0.f};

    const float* w2col = W2 + (size_t)f * D_ * D_ + tid;

    for (int kb = 0; kb < 4; ++kb) {
        float r[64];
        const float* p = w2col + (size_t)(kb * 64) * D_;
        #pragma unroll
        for (int j = 0; j < 64; ++j) r[j] = p[(size_t)j * D_];

        __syncthreads();
        #pragma unroll
        for (int j8 = 0; j8 < 8; ++j8) {
            union { s16x8 s; unsigned short u[8]; } pk;
            #pragma unroll
            for (int e = 0; e < 8; ++e) pk.u[e] = to_bf16_bits(r[j8 * 8 + e]);
            *reinterpret_cast<s16x8*>(&bW[tid][j8 * 8]) = pk.s;
        }
        __syncthreads();

        #pragma unroll
        for (int ks = 0; ks < 2; ++ks) {
            const int kg = kb * 64 + ks * 32 + lhi * 8;
            float w1r[8], b1r[8];
            #pragma unroll
            for (int e = 0; e < 8; ++e) { w1r[e] = w1s[kg + e]; b1r[e] = b1s[kg + e]; }

            s16x8 afrag[4];
            #pragma unroll
            for (int mt = 0; mt < 4; ++mt) {
                union { s16x8 s; unsigned short u[8]; } pk;
                #pragma unroll
                for (int e = 0; e < 8; ++e) {
                    float h = fmaf(xv[mt], w1r[e], b1r[e]);
                    pk.u[e] = to_bf16_bits(fmaxf(h, 0.f));
                }
                afrag[mt] = pk.s;
            }

            const int kl = ks * 32 + lhi * 8;
            #pragma unroll
            for (int nt = 0; nt < 8; ++nt) {
                s16x8 bfrag = *reinterpret_cast<const s16x8*>(
                    &bW[wn * 128 + nt * 16 + llo][kl]);
                #pragma unroll
                for (int mt = 0; mt < 4; ++mt)
                    acc[mt][nt] = __builtin_amdgcn_mfma_f32_16x16x32_bf16(
                        bfrag, afrag[mt], acc[mt][nt], 0, 0, 0);
            }
        }
    }

    const float* b2f = b2 + f * D_;
    float* obase = out + (size_t)(row0 + wm * 64 + llo) * ORS
                       + (f + 1) * D_ + wn * 128 + lhi * 4;
    #pragma unroll
    for (int nt = 0; nt < 8; ++nt) {
        f32x4 bv = *reinterpret_cast<const f32x4*>(&b2f[wn * 128 + nt * 16 + lhi * 4]);
        #pragma unroll
        for (int mt = 0; mt < 4; ++mt) {
            f32x4 v = acc[mt][nt] + bv;
            *reinterpret_cast<f32x4*>(obase + (size_t)mt * 16 * ORS + nt * 16) = v;
        }
    }
}

extern "C" void kernel_launch(void* const* d_in, const int* in_sizes, int n_in,
                              void* d_out, int out_size, void* d_ws, size_t ws_size,
                              hipStream_t stream)
{
    const float* x   = (const float*)d_in[0];
    const float* W1  = (const float*)d_in[1];
    const float* b1  = (const float*)d_in[2];
    const float* W2  = (const float*)d_in[3];
    const float* b2  = (const float*)d_in[4];
    const float* cls = (const float*)d_in[5];
    float* out = (float*)d_out;

    const size_t need = (size_t)F_ * D_ * D_ * sizeof(unsigned short); // 8 MiB
    if (ws_size >= need) {
        unsigned short* W2r = (unsigned short*)d_ws;
        femb_prep<<<F_ * 4, 256, 0, stream>>>(W2, W2r);
        femb_main11<<<32 * (B_ / 256), 512, 0, stream>>>(x, W1, b1, W2r, b2, cls, out);
    } else {
        femb_cls<<<(B_ * 64) / 256, 256, 0, stream>>>(cls, out);
        femb_main_fb<<<F_ * (B_ / 128), 256, 0, stream>>>(x, W1, b1, W2, b2, out);
    }
}

// Round 12
// 68.695 us; speedup vs baseline: 1.0730x; 1.0730x over previous
//
#include <hip/hip_runtime.h>
#include <hip/hip_bf16.h>

// FeatureEmbedding: out[b, f+1, e] = sum_d relu(x[b,f]*W1[f,d]+b1[f,d]) * W2[f,d,e] + b2[f,e]
//                   out[b, 0,   e] = cls_token[e]
// B=4096, F=64, D=256. Output f32 [4096][65][256].

#define B_  4096
#define F_  64
#define D_  256
#define ORS (65 * 256)   // out row stride (floats)

using f32x4  = __attribute__((ext_vector_type(4))) float;
using s16x8  = __attribute__((ext_vector_type(8))) short;

__device__ __forceinline__ unsigned short to_bf16_bits(float v) {
    __hip_bfloat16 h = __float2bfloat16(v);
    return *reinterpret_cast<unsigned short*>(&h);
}

// ---------------------------------------------------------------------------
// Prep (r10, proven): W2 f32 [f][k][e] -> W2r bf16; unit index
//   (((f*4 + cg)*4 + nt)*8 + ks)*64 + lane   (lane = lhi*16 + llo)
// holds the 8 bf16 of W2[f][k = ks*32+lhi*8 .. +8][n = cg*64+nt*16+llo].
// Wave loads of a (f,cg) stripe are 32 x 1KB contiguous.
// ---------------------------------------------------------------------------
__global__ __launch_bounds__(256) void femb_prep(
    const float* __restrict__ W2, unsigned short* __restrict__ W2r)
{
    const int blk = blockIdx.x;        // f*4 + kq (kq = 64-k quarter)
    const int f   = blk >> 2;
    const int kq  = blk & 3;
    const int t   = threadIdx.x;       // owns output column n = t

    const float* col = W2 + (size_t)f * D_ * D_ + (size_t)(kq * 64) * D_ + t;
    float r[64];
    #pragma unroll
    for (int j = 0; j < 64; ++j) r[j] = col[(size_t)j * D_];

    const int cg  = t >> 6;
    const int nt  = (t >> 4) & 3;
    const int llo = t & 15;

    #pragma unroll
    for (int j8 = 0; j8 < 8; ++j8) {
        union { s16x8 s; unsigned short u[8]; } pk;
        #pragma unroll
        for (int e = 0; e < 8; ++e) pk.u[e] = to_bf16_bits(r[j8 * 8 + e]);
        const int ks   = kq * 2 + (j8 >> 2);
        const int lhi  = j8 & 3;
        const size_t unit = ((size_t)((f * 4 + cg) * 4 + nt) * 8 + ks) * 64 + lhi * 16 + llo;
        *reinterpret_cast<s16x8*>(W2r + unit * 8) = pk.s;
    }
}

// ---------------------------------------------------------------------------
// Main (r10 champion + 2 tweaks): one block = (feature, 256-row group).
// 4 waves x 64 cols, B-stripe register-resident (32 x 1KB wave-loads).
// M streamed in 8 chunks of 32 rows; register-only K-loop (no barriers).
// Epilogue: 2 sub-chunks of 16 rows, STRICT eb ping-pong -> exactly ONE
// lgkm-only barrier per sub-chunk (stores never vmcnt-drained; the barrier's
// lgkm wait guarantees all waves' prior ds_reads completed, so the buffer is
// reusable without a trailing bar). Contiguous 1KB-row stores.
// Grid 1024: co-resident blocks cover a 2x denser row window (write-page
// locality probe). f==0 blocks also write the cls row.
// ---------------------------------------------------------------------------
__global__ __launch_bounds__(256, 2) void femb_main12(
    const float* __restrict__ x,  const float* __restrict__ W1,
    const float* __restrict__ b1, const unsigned short* __restrict__ W2r,
    const float* __restrict__ b2, const float* __restrict__ cls,
    float* __restrict__ out)
{
    __shared__ float w1s[D_];
    __shared__ float b1s[D_];
    __shared__ float xs[256];
    __shared__ __align__(16) float eb[2][16 * 260];

    const int tid  = threadIdx.x;
    const int bid  = blockIdx.x;
    const int f    = bid & 63;         // same-f blocks step by 64
    const int row0 = (bid >> 6) << 8;  // 16 row-groups of 256

    w1s[tid] = W1[f * D_ + tid];
    b1s[tid] = b1[f * D_ + tid];
    xs[tid]  = x[(size_t)(row0 + tid) * F_ + f];

    const int lane = tid & 63;
    const int w    = tid >> 6;   // wave id = 64-col group
    const int llo  = lane & 15;
    const int lhi  = lane >> 4;

    // ---- B-stripe -> registers: 32 x 1KB contiguous wave-loads ----
    s16x8 breg[4][8];
    const unsigned short* gb = W2r + (size_t)(f * 4 + w) * 16384;
    #pragma unroll
    for (int nt = 0; nt < 4; ++nt)
        #pragma unroll
        for (int ks = 0; ks < 8; ++ks)
            breg[nt][ks] = *reinterpret_cast<const s16x8*>(
                gb + ((nt * 8 + ks) * 64 + lane) * 8);

    __syncthreads();   // xs/w1s/b1s ready

    f32x4 b2v  = *reinterpret_cast<const f32x4*>(&b2[f * D_ + lane * 4]);
    f32x4 clsv = *reinterpret_cast<const f32x4*>(cls + lane * 4);

    // lgkmcnt-only barrier: orders LDS without draining global stores.
#define EPI_BAR()                                                              \
    do {                                                                       \
        asm volatile("s_waitcnt lgkmcnt(0)" ::: "memory");                     \
        __builtin_amdgcn_s_barrier();                                          \
        asm volatile("" ::: "memory");                                         \
    } while (0)

    for (int ch = 0; ch < 8; ++ch) {
        // ---- K-loop rows [ch*32, ch*32+32): register-only, no barriers ----
        const float xv0 = xs[ch * 32 + llo];
        const float xv1 = xs[ch * 32 + 16 + llo];

        f32x4 acc[2][4];
        #pragma unroll
        for (int mt = 0; mt < 2; ++mt)
            #pragma unroll
            for (int nt = 0; nt < 4; ++nt)
                acc[mt][nt] = (f32x4){0.f, 0.f, 0.f, 0.f};

        #pragma unroll
        for (int ks = 0; ks < 8; ++ks) {
            const int kg = ks * 32 + lhi * 8;
            f32x4 w1a = *reinterpret_cast<const f32x4*>(&w1s[kg]);
            f32x4 w1b = *reinterpret_cast<const f32x4*>(&w1s[kg + 4]);
            f32x4 b1a = *reinterpret_cast<const f32x4*>(&b1s[kg]);
            f32x4 b1b = *reinterpret_cast<const f32x4*>(&b1s[kg + 4]);

            s16x8 afrag[2];
            #pragma unroll
            for (int mt = 0; mt < 2; ++mt) {
                const float xv = mt ? xv1 : xv0;
                union { s16x8 sv; unsigned short u[8]; } pk;
                #pragma unroll
                for (int e = 0; e < 4; ++e) {
                    pk.u[e]     = to_bf16_bits(fmaxf(fmaf(xv, w1a[e], b1a[e]), 0.f));
                    pk.u[e + 4] = to_bf16_bits(fmaxf(fmaf(xv, w1b[e], b1b[e]), 0.f));
                }
                afrag[mt] = pk.sv;
            }

            #pragma unroll
            for (int nt = 0; nt < 4; ++nt)
                #pragma unroll
                for (int mt = 0; mt < 2; ++mt)
                    acc[mt][nt] = __builtin_amdgcn_mfma_f32_16x16x32_bf16(
                        breg[nt][ks], afrag[mt], acc[mt][nt], 0, 0, 0);
        }

        // ---- Epilogue: 2 sub-chunks of 16 rows, 1 bar each (ping-pong) ----
        // acc layout (verified): row = ch*32 + mt*16 + llo ;
        //                        col = w*64 + nt*16 + lhi*4 + r
        #pragma unroll
        for (int sc = 0; sc < 2; ++sc) {
            float* ebuf = eb[sc];
            #pragma unroll
            for (int nt = 0; nt < 4; ++nt)
                *reinterpret_cast<f32x4*>(
                    &ebuf[llo * 260 + w * 64 + nt * 16 + lhi * 4]) = acc[sc][nt];
            EPI_BAR();   // W(ebuf) visible; also retires prior reads of ebuf's twin
            #pragma unroll
            for (int i = 0; i < 4; ++i) {
                const int lr = w * 4 + i;
                const size_t grow = (size_t)(row0 + ch * 32 + sc * 16 + lr);
                f32x4 v = *reinterpret_cast<const f32x4*>(&ebuf[lr * 260 + lane * 4]) + b2v;
                *reinterpret_cast<f32x4*>(out + grow * ORS + (f + 1) * D_ + lane * 4) = v;
                if (f == 0)
                    *reinterpret_cast<f32x4*>(out + grow * ORS + lane * 4) = clsv;
            }
            // no trailing bar: next sub-chunk writes the OTHER buffer; its
            // barrier's lgkm wait retires this sub-chunk's ds_reads first.
        }
    }
#undef EPI_BAR
}

// ---------------------------------------------------------------------------
// Fallback path (round-1, proven) if ws too small: cls kernel + direct main.
// ---------------------------------------------------------------------------
__global__ void femb_cls(const float* __restrict__ cls, float* __restrict__ out)
{
    int i = blockIdx.x * 256 + threadIdx.x;
    int b = i >> 6;
    int q = i & 63;
    f32x4 v = *reinterpret_cast<const f32x4*>(cls + q * 4);
    *reinterpret_cast<f32x4*>(out + (size_t)b * ORS + q * 4) = v;
}

__global__ __launch_bounds__(256, 2) void femb_main_fb(
    const float* __restrict__ x,  const float* __restrict__ W1,
    const float* __restrict__ b1, const float* __restrict__ W2,
    const float* __restrict__ b2, float* __restrict__ out)
{
    __shared__ float w1s[D_];
    __shared__ float b1s[D_];
    __shared__ float xs[128];
    __shared__ __align__(16) unsigned short bW[256][72];

    const int tid  = threadIdx.x;
    const int bid  = blockIdx.x;
    const int f    = bid & 63;
    const int row0 = (bid >> 6) << 7;

    w1s[tid] = W1[f * D_ + tid];
    b1s[tid] = b1[f * D_ + tid];
    if (tid < 128) xs[tid] = x[(size_t)(row0 + tid) * F_ + f];

    const int lane = tid & 63;
    const int wid  = tid >> 6;
    const int wm   = wid >> 1;
    const int wn   = wid & 1;
    const int llo  = lane & 15;
    const int lhi  = lane >> 4;

    __syncthreads();

    float xv[4];
    #pragma unroll
    for (int mt = 0; mt < 4; ++mt) xv[mt] = xs[wm * 64 + mt * 16 + llo];

    f32x4 acc[4][8];
    #pragma unroll
    for (int mt = 0; mt < 4; ++mt)
        #pragma unroll
        for (int nt = 0; nt < 8; ++nt)
            acc[mt][nt] = (f32x4){0.f, 0.f, 0.f, 0.f};

    const float* w2col = W2 + (size_t)f * D_ * D_ + tid;

    for (int kb = 0; kb < 4; ++kb) {
        float r[64];
        const float* p = w2col + (size_t)(kb * 64) * D_;
        #pragma unroll
        for (int j = 0; j < 64; ++j) r[j] = p[(size_t)j * D_];

        __syncthreads();
        #pragma unroll
        for (int j8 = 0; j8 < 8; ++j8) {
            union { s16x8 s; unsigned short u[8]; } pk;
            #pragma unroll
            for (int e = 0; e < 8; ++e) pk.u[e] = to_bf16_bits(r[j8 * 8 + e]);
            *reinterpret_cast<s16x8*>(&bW[tid][j8 * 8]) = pk.s;
        }
        __syncthreads();

        #pragma unroll
        for (int ks = 0; ks < 2; ++ks) {
            const int kg = kb * 64 + ks * 32 + lhi * 8;
            float w1r[8], b1r[8];
            #pragma unroll
            for (int e = 0; e < 8; ++e) { w1r[e] = w1s[kg + e]; b1r[e] = b1s[kg + e]; }

            s16x8 afrag[4];
            #pragma unroll
            for (int mt = 0; mt < 4; ++mt) {
                union { s16x8 s; unsigned short u[8]; } pk;
                #pragma unroll
                for (int e = 0; e < 8; ++e) {
                    float h = fmaf(xv[mt], w1r[e], b1r[e]);
                    pk.u[e] = to_bf16_bits(fmaxf(h, 0.f));
                }
                afrag[mt] = pk.s;
            }

            const int kl = ks * 32 + lhi * 8;
            #pragma unroll
            for (int nt = 0; nt < 8; ++nt) {
                s16x8 bfrag = *reinterpret_cast<const s16x8*>(
                    &bW[wn * 128 + nt * 16 + llo][kl]);
                #pragma unroll
                for (int mt = 0; mt < 4; ++mt)
                    acc[mt][nt] = __builtin_amdgcn_mfma_f32_16x16x32_bf16(
                        bfrag, afrag[mt], acc[mt][nt], 0, 0, 0);
            }
        }
    }

    const float* b2f = b2 + f * D_;
    float* obase = out + (size_t)(row0 + wm * 64 + llo) * ORS
                       + (f + 1) * D_ + wn * 128 + lhi * 4;
    #pragma unroll
    for (int nt = 0; nt < 8; ++nt) {
        f32x4 bv = *reinterpret_cast<const f32x4*>(&b2f[wn * 128 + nt * 16 + lhi * 4]);
        #pragma unroll
        for (int mt = 0; mt < 4; ++mt) {
            f32x4 v = acc[mt][nt] + bv;
            *reinterpret_cast<f32x4*>(obase + (size_t)mt * 16 * ORS + nt * 16) = v;
        }
    }
}

extern "C" void kernel_launch(void* const* d_in, const int* in_sizes, int n_in,
                              void* d_out, int out_size, void* d_ws, size_t ws_size,
                              hipStream_t stream)
{
    const float* x   = (const float*)d_in[0];
    const float* W1  = (const float*)d_in[1];
    const float* b1  = (const float*)d_in[2];
    const float* W2  = (const float*)d_in[3];
    const float* b2  = (const float*)d_in[4];
    const float* cls = (const float*)d_in[5];
    float* out = (float*)d_out;

    const size_t need = (size_t)F_ * D_ * D_ * sizeof(unsigned short); // 8 MiB
    if (ws_size >= need) {
        unsigned short* W2r = (unsigned short*)d_ws;
        femb_prep<<<F_ * 4, 256, 0, stream>>>(W2, W2r);
        femb_main12<<<F_ * (B_ / 256), 256, 0, stream>>>(x, W1, b1, W2r, b2, cls, out);
    } else {
        femb_cls<<<(B_ * 64) / 256, 256, 0, stream>>>(cls, out);
        femb_main_fb<<<F_ * (B_ / 128), 256, 0, stream>>>(x, W1, b1, W2, b2, out);
    }
}